// Round 6
// baseline (291.762 us; speedup 1.0000x reference)
//
#include <hip/hip_runtime.h>
#include <hip/hip_bf16.h>
#include <stdint.h>

// Problem constants (from reference)
#define BSZ   16384
#define INDIM 256
#define HID   1024
#define NA    512
#define NE    4
#define BM 128
#define BN 128
#define BK 32
// padded-sorted row space: each head segment 128-aligned
#define PADM (BSZ + NE * BM)   // 16896

typedef __hip_bfloat16 bf16;
typedef __attribute__((ext_vector_type(8))) short    short8;
typedef __attribute__((ext_vector_type(4))) float    f32x4;
typedef __attribute__((ext_vector_type(8))) unsigned short u16x8;

// ---------------- async global->LDS (16B per lane) ----------------
// HW semantics: LDS dest = wave-uniform base + lane*16; global src is per-lane.
__device__ __forceinline__ void gload16(const void* g, void* l) {
  __builtin_amdgcn_global_load_lds(
      (__attribute__((address_space(1))) void*)g,
      (__attribute__((address_space(3))) void*)l, 16, 0, 0);
}

// stage one 128x32 A-tile + 128x32 B-tile into LDS (async, 4 gload16/thread)
__device__ __forceinline__ void stage_tile(const bf16* __restrict__ A,
                                           const bf16* __restrict__ Bt,
                                           int bm0, int bn0, int k0, int K,
                                           int t, int w, bf16* sa, bf16* sb) {
#pragma unroll
  for (int s = 0; s < 2; ++s) {
    gload16(A + (size_t)(bm0 + s * 64 + (t >> 2)) * K + k0 + (t & 3) * 8,
            (char*)sa + s * 4096 + w * 1024);
    gload16(Bt + (size_t)(bn0 + s * 64 + (t >> 2)) * K + k0 + (t & 3) * 8,
            (char*)sb + s * 4096 + w * 1024);
  }
}

// ---------------- routing ----------------
__global__ void k_zero(int* cnt, int* cursor) {
  if (threadIdx.x < NE) { cnt[threadIdx.x] = 0; cursor[threadIdx.x] = 0; }
}

// per-block LDS histogram -> 4 global atomics per block
__global__ void k_count(const float* __restrict__ x, int* __restrict__ cnt) {
  __shared__ int h[NE];
  const int t = threadIdx.x;
  if (t < NE) h[t] = 0;
  __syncthreads();
  int i = blockIdx.x * blockDim.x + t;
  int r = (int)x[(size_t)i * INDIM + (INDIM - 1)];
  if (r >= 0 && r < NE) atomicAdd(&h[r], 1);
  __syncthreads();
  if (t < NE && h[t] > 0) atomicAdd(&cnt[t], h[t]);
}

// padded prefix: segment e starts at poff[e], size ceil(cnt/BM)*BM; poff[NE]=total
__global__ void k_prefix(const int* __restrict__ cnt, int* __restrict__ poff) {
  if (threadIdx.x == 0) {
    int a = 0;
    for (int e = 0; e < NE; ++e) {
      poff[e] = a;
      a += (cnt[e] + BM - 1) / BM * BM;
    }
    poff[NE] = a;
  }
}

// block claims contiguous chunk per regime; emits both directions of the perm
__global__ void k_scatter(const float* __restrict__ x, const int* __restrict__ poff,
                          int* __restrict__ cursor, int* __restrict__ sortidx,
                          int* __restrict__ rowid) {
  __shared__ int h[NE], base[NE];
  const int t = threadIdx.x;
  if (t < NE) h[t] = 0;
  __syncthreads();
  int i = blockIdx.x * blockDim.x + t;
  int r = (int)x[(size_t)i * INDIM + (INDIM - 1)];
  int lrank = -1;
  if (r >= 0 && r < NE) lrank = atomicAdd(&h[r], 1);
  __syncthreads();
  if (t < NE) base[t] = (h[t] > 0) ? atomicAdd(&cursor[t], h[t]) : 0;
  __syncthreads();
  if (r >= 0 && r < NE) {
    int p = poff[r] + base[r] + lrank;
    sortidx[i] = p;
    rowid[p] = i;
  }
}

// fp32 -> bf16 cast INTO PERMUTED ROW ORDER. 8 cols/thread; 32 consecutive
// threads share a row -> writes are contiguous 512B segments per row.
__global__ void k_cast_perm(const float* __restrict__ x, const int* __restrict__ sortidx,
                            bf16* __restrict__ xb) {
  int i = blockIdx.x * blockDim.x + threadIdx.x;   // [0, BSZ*INDIM/8)
  int row = i >> 5, c8 = (i & 31) * 8;
  int drow = sortidx[row];
  const float4* s = (const float4*)(x + (size_t)row * INDIM + c8);
  float4 a = s[0], b = s[1];
  bf16 t[8];
  t[0] = __float2bfloat16(a.x); t[1] = __float2bfloat16(a.y);
  t[2] = __float2bfloat16(a.z); t[3] = __float2bfloat16(a.w);
  t[4] = __float2bfloat16(b.x); t[5] = __float2bfloat16(b.y);
  t[6] = __float2bfloat16(b.z); t[7] = __float2bfloat16(b.w);
  *(u16x8*)(xb + (size_t)drow * INDIM + c8) = *(u16x8*)t;
}

// fp32 [R][C] -> bf16 [C][R], batched on z. grid(C/32, R/32, batch), block(32,8)
__global__ void k_transpose(const float* __restrict__ src, bf16* __restrict__ dst,
                            int R, int C) {
  __shared__ float tile[32][33];
  const float* s = src + (size_t)blockIdx.z * R * C;
  bf16* d = dst + (size_t)blockIdx.z * R * C;
  int c0 = blockIdx.x * 32, r0 = blockIdx.y * 32;
  int tx = threadIdx.x, ty = threadIdx.y;
#pragma unroll
  for (int i = 0; i < 32; i += 8)
    tile[ty + i][tx] = s[(size_t)(r0 + ty + i) * C + c0 + tx];
  __syncthreads();
#pragma unroll
  for (int i = 0; i < 32; i += 8)
    d[(size_t)(c0 + ty + i) * R + r0 + tx] = __float2bfloat16(tile[tx][ty + i]);
}

// ---------------- GEMM: C = relu(A @ Bt^T + bias) -> bf16 ----------------
// A: [M][K] bf16 row-major (padded-sorted), Bt: [N][K] bf16, Out: [M][N] bf16
// 128x128 tile, BK=32, 4 waves. Double-buffered LDS: next tile's
// global_load_lds issued BEFORE current tile's compute; one barrier per
// K-step (compiler's vmcnt(0)-before-barrier then lands after the MFMA work).
// XCD-contiguous block swizzle (grid count % 8 == 0).
__global__ __launch_bounds__(256) void k_gemm_relu(
    const bf16* __restrict__ A, const bf16* __restrict__ Bt,
    const float* __restrict__ bias, bf16* __restrict__ Out,
    int N, int K) {
  __shared__ bf16 sA[2][BM * BK];
  __shared__ bf16 sB[2][BN * BK];
  const int t = threadIdx.x, w = t >> 6, l = t & 63;
  const int wr = w >> 1, wc = w & 1;
  // XCD-aware remap: each XCD gets a contiguous chunk of (by,bx) work ids
  const int nwg = gridDim.x * gridDim.y;
  const int id = blockIdx.y * gridDim.x + blockIdx.x;
  const int swz = (id & 7) * (nwg >> 3) + (id >> 3);
  const int bm0 = (swz / gridDim.x) * BM, bn0 = (swz % gridDim.x) * BN;
  const int lr = l & 15, lk = (l >> 4) * 8;
  f32x4 acc[4][4] = {};

  stage_tile(A, Bt, bm0, bn0, 0, K, t, w, sA[0], sB[0]);
  __syncthreads();   // drains vmcnt(0): tile 0 visible
  int cur = 0;
  for (int k0 = 0; k0 < K; k0 += BK) {
    const bool last = (k0 + BK >= K);
    if (!last)
      stage_tile(A, Bt, bm0, bn0, k0 + BK, K, t, w, sA[cur ^ 1], sB[cur ^ 1]);
    short8 af[4], bfr[4];
#pragma unroll
    for (int m = 0; m < 4; ++m)
      af[m] = *(const short8*)&sA[cur][(wr * 64 + m * 16 + lr) * BK + lk];
#pragma unroll
    for (int n = 0; n < 4; ++n)
      bfr[n] = *(const short8*)&sB[cur][(wc * 64 + n * 16 + lr) * BK + lk];
#pragma unroll
    for (int m = 0; m < 4; ++m)
#pragma unroll
      for (int n = 0; n < 4; ++n)
        acc[m][n] = __builtin_amdgcn_mfma_f32_16x16x32_bf16(af[m], bfr[n], acc[m][n], 0, 0, 0);
    if (!last) { __syncthreads(); cur ^= 1; }  // next tile staged + all reads done
  }

#pragma unroll
  for (int m = 0; m < 4; ++m) {
#pragma unroll
    for (int n = 0; n < 4; ++n) {
      int col = bn0 + wc * 64 + n * 16 + lr;
      float bv = bias[col];
#pragma unroll
      for (int r = 0; r < 4; ++r) {
        int row = bm0 + wr * 64 + m * 16 + (l >> 4) * 4 + r;
        float v = acc[m][n][r] + bv;
        v = v > 0.f ? v : 0.f;
        Out[(size_t)row * N + col] = __float2bfloat16(v);
      }
    }
  }
}

// ---------------- GEMM3: dense per-head GEMM on padded-sorted rows ----------------
// grid (NA/BN=4, PADM/BM=132) -> 528 blocks (%8==0). Same dbuf+swizzle structure.
__global__ __launch_bounds__(256) void k_gemm_head(
    const bf16* __restrict__ H,      // [PADM][HID] padded-sorted
    const bf16* __restrict__ Wht,    // [NE][NA][HID]
    const float* __restrict__ bh,    // [NE][NA]
    const int* __restrict__ poff,    // [NE+1]
    const int* __restrict__ cnt,     // [NE]
    const int* __restrict__ rowid,   // [PADM]
    float* __restrict__ Out) {
  const int nwg = gridDim.x * gridDim.y;
  const int id = blockIdx.y * gridDim.x + blockIdx.x;
  const int swz = (id & 7) * (nwg >> 3) + (id >> 3);
  const int mb0 = (swz / gridDim.x) * BM;
  const int bn0 = (swz % gridDim.x) * BN;
  if (mb0 >= poff[NE]) return;   // block-uniform exit (before any barrier)
  int e = 0;
#pragma unroll
  for (int k = 1; k < NE; ++k) if (mb0 >= poff[k]) e = k;
  const int pend = poff[e] + cnt[e];   // rows >= pend are padding

  const int t = threadIdx.x, w = t >> 6, l = t & 63;
  const int wr = w >> 1, wc = w & 1;
  const int lr = l & 15, lk = (l >> 4) * 8;
  const bf16* Wt = Wht + (size_t)e * NA * HID;

  __shared__ bf16 sA[2][BM * BK];
  __shared__ bf16 sB[2][BN * BK];
  f32x4 acc[4][4] = {};

  stage_tile(H, Wt, mb0, bn0, 0, HID, t, w, sA[0], sB[0]);
  __syncthreads();
  int cur = 0;
  for (int k0 = 0; k0 < HID; k0 += BK) {
    const bool last = (k0 + BK >= HID);
    if (!last)
      stage_tile(H, Wt, mb0, bn0, k0 + BK, HID, t, w, sA[cur ^ 1], sB[cur ^ 1]);
    short8 af[4], bfr[4];
#pragma unroll
    for (int m = 0; m < 4; ++m)
      af[m] = *(const short8*)&sA[cur][(wr * 64 + m * 16 + lr) * BK + lk];
#pragma unroll
    for (int n = 0; n < 4; ++n)
      bfr[n] = *(const short8*)&sB[cur][(wc * 64 + n * 16 + lr) * BK + lk];
#pragma unroll
    for (int m = 0; m < 4; ++m)
#pragma unroll
      for (int n = 0; n < 4; ++n)
        acc[m][n] = __builtin_amdgcn_mfma_f32_16x16x32_bf16(af[m], bfr[n], acc[m][n], 0, 0, 0);
    if (!last) { __syncthreads(); cur ^= 1; }
  }

#pragma unroll
  for (int m = 0; m < 4; ++m) {
#pragma unroll
    for (int r = 0; r < 4; ++r) {
      int ps = mb0 + wr * 64 + m * 16 + (l >> 4) * 4 + r;
      if (ps < pend) {
        int row = rowid[ps];
#pragma unroll
        for (int n = 0; n < 4; ++n) {
          int col = bn0 + wc * 64 + n * 16 + lr;
          float v = acc[m][n][r] + bh[e * NA + col];
          float sp = (v > 20.f) ? v : log1pf(expf(v));
          Out[(size_t)row * NA + col] = sp + 1.f;
        }
      }
    }
  }
}

// ---------------- launch ----------------
extern "C" void kernel_launch(void* const* d_in, const int* in_sizes, int n_in,
                              void* d_out, int out_size, void* d_ws, size_t ws_size,
                              hipStream_t stream) {
  const float* x  = (const float*)d_in[0];
  const float* W1 = (const float*)d_in[1];
  const float* b1 = (const float*)d_in[2];
  const float* W2 = (const float*)d_in[3];
  const float* b2 = (const float*)d_in[4];
  const float* Wh = (const float*)d_in[5];
  const float* bh = (const float*)d_in[6];
  float* out = (float*)d_out;

  // workspace carve (all 256B-aligned)
  char* p = (char*)d_ws;
  bf16* xb  = (bf16*)p; p += (size_t)PADM * INDIM * 2;  // 8.7 MiB (permuted)
  bf16* w1t = (bf16*)p; p += (size_t)HID * INDIM * 2;   // 512 KiB
  bf16* w2t = (bf16*)p; p += (size_t)HID * HID * 2;     // 2 MiB
  bf16* wht = (bf16*)p; p += (size_t)NE * NA * HID * 2; // 4 MiB
  bf16* h1b = (bf16*)p; p += (size_t)PADM * HID * 2;    // 34.6 MiB (permuted)
  bf16* h2b = (bf16*)p; p += (size_t)PADM * HID * 2;    // 34.6 MiB (permuted)
  int* sortidx = (int*)p; p += (size_t)BSZ * 4;         // orig -> padded pos
  int* rowid   = (int*)p; p += (size_t)PADM * 4;        // padded pos -> orig
  int* cnt    = (int*)p; p += 256;
  int* poff   = (int*)p; p += 256;
  int* cursor = (int*)p; p += 256;

  const int MB = PADM / BM;  // 132 m-blocks over padded row space

  // routing (counting sort of rows by regime, hierarchical histogram)
  k_zero<<<1, 64, 0, stream>>>(cnt, cursor);
  k_count<<<BSZ / 256, 256, 0, stream>>>(x, cnt);
  k_prefix<<<1, 64, 0, stream>>>(cnt, poff);
  k_scatter<<<BSZ / 256, 256, 0, stream>>>(x, poff, cursor, sortidx, rowid);

  // bf16 conversions (x cast lands in permuted row order)
  k_cast_perm<<<BSZ * (INDIM / 8) / 256, 256, 0, stream>>>(x, sortidx, xb);
  k_transpose<<<dim3(HID / 32, INDIM / 32, 1), dim3(32, 8), 0, stream>>>(W1, w1t, INDIM, HID);
  k_transpose<<<dim3(HID / 32, HID / 32, 1), dim3(32, 8), 0, stream>>>(W2, w2t, HID, HID);
  k_transpose<<<dim3(NA / 32, HID / 32, NE), dim3(32, 8), 0, stream>>>(Wh, wht, HID, NA);

  // GEMM1: h1 = relu(xs @ W1 + b1)   (padded rows compute garbage, masked later)
  k_gemm_relu<<<dim3(HID / BN, MB), 256, 0, stream>>>(xb, w1t, b1, h1b, HID, INDIM);
  // GEMM2: h2 = relu(h1 @ W2 + b2)
  k_gemm_relu<<<dim3(HID / BN, MB), 256, 0, stream>>>(h1b, w2t, b2, h2b, HID, HID);
  // GEMM3: dense per-head, softplus+1, scatter store via rowid
  k_gemm_head<<<dim3(NA / BN, MB), 256, 0, stream>>>(h2b, wht, bh, poff, cnt, rowid, out);
}

// Round 7
// 288.280 us; speedup vs baseline: 1.0121x; 1.0121x over previous
//
#include <hip/hip_runtime.h>
#include <hip/hip_bf16.h>
#include <stdint.h>

// Problem constants (from reference)
#define BSZ   16384
#define INDIM 256
#define HID   1024
#define NA    512
#define NE    4
#define BM 128
#define BN 128
#define BK 64
// padded-sorted row space: each head segment 128-aligned
#define PADM (BSZ + NE * BM)   // 16896

typedef __hip_bfloat16 bf16;
typedef __attribute__((ext_vector_type(8))) short    short8;
typedef __attribute__((ext_vector_type(4))) float    f32x4;
typedef __attribute__((ext_vector_type(8))) unsigned short u16x8;

// ---------------- async global->LDS (16B per lane) ----------------
// HW semantics: LDS dest = wave-uniform base + lane*16; global src is per-lane.
__device__ __forceinline__ void gload16(const void* g, void* l) {
  __builtin_amdgcn_global_load_lds(
      (__attribute__((address_space(1))) void*)g,
      (__attribute__((address_space(3))) void*)l, 16, 0, 0);
}

// ---------------- routing ----------------
__global__ void k_zero(int* cnt, int* cursor) {
  if (threadIdx.x < NE) { cnt[threadIdx.x] = 0; cursor[threadIdx.x] = 0; }
}

// per-block LDS histogram -> 4 global atomics per block
__global__ void k_count(const float* __restrict__ x, int* __restrict__ cnt) {
  __shared__ int h[NE];
  const int t = threadIdx.x;
  if (t < NE) h[t] = 0;
  __syncthreads();
  int i = blockIdx.x * blockDim.x + t;
  int r = (int)x[(size_t)i * INDIM + (INDIM - 1)];
  if (r >= 0 && r < NE) atomicAdd(&h[r], 1);
  __syncthreads();
  if (t < NE && h[t] > 0) atomicAdd(&cnt[t], h[t]);
}

// padded prefix: segment e starts at poff[e], size ceil(cnt/BM)*BM; poff[NE]=total
__global__ void k_prefix(const int* __restrict__ cnt, int* __restrict__ poff) {
  if (threadIdx.x == 0) {
    int a = 0;
    for (int e = 0; e < NE; ++e) {
      poff[e] = a;
      a += (cnt[e] + BM - 1) / BM * BM;
    }
    poff[NE] = a;
  }
}

// block claims contiguous chunk per regime; emits both directions of the perm
__global__ void k_scatter(const float* __restrict__ x, const int* __restrict__ poff,
                          int* __restrict__ cursor, int* __restrict__ sortidx,
                          int* __restrict__ rowid) {
  __shared__ int h[NE], base[NE];
  const int t = threadIdx.x;
  if (t < NE) h[t] = 0;
  __syncthreads();
  int i = blockIdx.x * blockDim.x + t;
  int r = (int)x[(size_t)i * INDIM + (INDIM - 1)];
  int lrank = -1;
  if (r >= 0 && r < NE) lrank = atomicAdd(&h[r], 1);
  __syncthreads();
  if (t < NE) base[t] = (h[t] > 0) ? atomicAdd(&cursor[t], h[t]) : 0;
  __syncthreads();
  if (r >= 0 && r < NE) {
    int p = poff[r] + base[r] + lrank;
    sortidx[i] = p;
    rowid[p] = i;
  }
}

// fp32 -> bf16 cast INTO PERMUTED ROW ORDER. 8 cols/thread; 32 consecutive
// threads share a row -> writes are contiguous 512B segments per row.
__global__ void k_cast_perm(const float* __restrict__ x, const int* __restrict__ sortidx,
                            bf16* __restrict__ xb) {
  int i = blockIdx.x * blockDim.x + threadIdx.x;   // [0, BSZ*INDIM/8)
  int row = i >> 5, c8 = (i & 31) * 8;
  int drow = sortidx[row];
  const float4* s = (const float4*)(x + (size_t)row * INDIM + c8);
  float4 a = s[0], b = s[1];
  bf16 t[8];
  t[0] = __float2bfloat16(a.x); t[1] = __float2bfloat16(a.y);
  t[2] = __float2bfloat16(a.z); t[3] = __float2bfloat16(a.w);
  t[4] = __float2bfloat16(b.x); t[5] = __float2bfloat16(b.y);
  t[6] = __float2bfloat16(b.z); t[7] = __float2bfloat16(b.w);
  *(u16x8*)(xb + (size_t)drow * INDIM + c8) = *(u16x8*)t;
}

// fp32 [R][C] -> bf16 [C][R], batched on z. grid(C/32, R/32, batch), block(32,8)
__global__ void k_transpose(const float* __restrict__ src, bf16* __restrict__ dst,
                            int R, int C) {
  __shared__ float tile[32][33];
  const float* s = src + (size_t)blockIdx.z * R * C;
  bf16* d = dst + (size_t)blockIdx.z * R * C;
  int c0 = blockIdx.x * 32, r0 = blockIdx.y * 32;
  int tx = threadIdx.x, ty = threadIdx.y;
#pragma unroll
  for (int i = 0; i < 32; i += 8)
    tile[ty + i][tx] = s[(size_t)(r0 + ty + i) * C + c0 + tx];
  __syncthreads();
#pragma unroll
  for (int i = 0; i < 32; i += 8)
    d[(size_t)(c0 + ty + i) * R + r0 + tx] = __float2bfloat16(tile[tx][ty + i]);
}

// ---------------- GEMM core (BK=64, 2-barrier, pointer-increment) ----------------
// Staging slot s covers rows [s*32, s*32+32): 256 thr * 16B = 4096 B = 32 rows.
// Thread t stages row (t>>3), byte col (t&7)*16 of its slot.
#define FRAG_READS(sa, sb, kh)                                                  \
  short8 af[4], bfr[4];                                                         \
  _Pragma("unroll")                                                             \
  for (int m = 0; m < 4; ++m)                                                   \
    af[m] = *(const short8*)&sa[(wr * 64 + m * 16 + lr) * BK + (kh) * 32 + lk]; \
  _Pragma("unroll")                                                             \
  for (int n = 0; n < 4; ++n)                                                   \
    bfr[n] = *(const short8*)&sb[(wc * 64 + n * 16 + lr) * BK + (kh) * 32 + lk];

// ---------------- GEMM: C = relu(A @ Bt^T + bias) -> bf16 ----------------
__global__ __launch_bounds__(256) void k_gemm_relu(
    const bf16* __restrict__ A, const bf16* __restrict__ Bt,
    const float* __restrict__ bias, bf16* __restrict__ Out,
    int N, int K) {
  __shared__ bf16 sA[BM * BK];   // 16 KiB
  __shared__ bf16 sB[BN * BK];   // 16 KiB
  const int t = threadIdx.x, w = t >> 6, l = t & 63;
  const int wr = w >> 1, wc = w & 1;
  const int bm0 = blockIdx.y * BM, bn0 = blockIdx.x * BN;
  const int lr = l & 15, lk = (l >> 4) * 8;
  f32x4 acc[4][4] = {};

  // per-thread staging pointers, advanced by BK each iteration
  const bf16* pA = A + (size_t)(bm0 + (t >> 3)) * K + (t & 7) * 8;
  const bf16* pB = Bt + (size_t)(bn0 + (t >> 3)) * K + (t & 7) * 8;
  const size_t slotstride = (size_t)32 * K;   // 32 rows per slot

  for (int k0 = 0; k0 < K; k0 += BK) {
    __syncthreads();   // prior iter's ds_reads done before overwrite
#pragma unroll
    for (int s = 0; s < 4; ++s) {
      gload16(pA + s * slotstride, (char*)sA + s * 4096 + w * 1024);
      gload16(pB + s * slotstride, (char*)sB + s * 4096 + w * 1024);
    }
    pA += BK; pB += BK;
    __syncthreads();   // barrier drains vmcnt(0): tile visible
#pragma unroll
    for (int kh = 0; kh < 2; ++kh) {
      FRAG_READS(sA, sB, kh)
#pragma unroll
      for (int m = 0; m < 4; ++m)
#pragma unroll
        for (int n = 0; n < 4; ++n)
          acc[m][n] = __builtin_amdgcn_mfma_f32_16x16x32_bf16(af[m], bfr[n], acc[m][n], 0, 0, 0);
    }
  }

#pragma unroll
  for (int m = 0; m < 4; ++m) {
#pragma unroll
    for (int n = 0; n < 4; ++n) {
      int col = bn0 + wc * 64 + n * 16 + lr;
      float bv = bias[col];
#pragma unroll
      for (int r = 0; r < 4; ++r) {
        int row = bm0 + wr * 64 + m * 16 + (l >> 4) * 4 + r;
        float v = acc[m][n][r] + bv;
        v = v > 0.f ? v : 0.f;
        Out[(size_t)row * N + col] = __float2bfloat16(v);
      }
    }
  }
}

// ---------------- GEMM3: dense per-head GEMM on padded-sorted rows ----------------
// grid (NA/BN=4, PADM/BM=132). Head derived from poff; softplus+1; scatter store.
__global__ __launch_bounds__(256) void k_gemm_head(
    const bf16* __restrict__ H,      // [PADM][HID] padded-sorted
    const bf16* __restrict__ Wht,    // [NE][NA][HID]
    const float* __restrict__ bh,    // [NE][NA]
    const int* __restrict__ poff,    // [NE+1]
    const int* __restrict__ cnt,     // [NE]
    const int* __restrict__ rowid,   // [PADM]
    float* __restrict__ Out) {
  const int mb0 = blockIdx.y * BM;
  if (mb0 >= poff[NE]) return;   // block-uniform exit (before any barrier)
  int e = 0;
#pragma unroll
  for (int k = 1; k < NE; ++k) if (mb0 >= poff[k]) e = k;
  const int pend = poff[e] + cnt[e];   // rows >= pend are padding

  const int t = threadIdx.x, w = t >> 6, l = t & 63;
  const int wr = w >> 1, wc = w & 1;
  const int bn0 = blockIdx.x * BN;
  const int lr = l & 15, lk = (l >> 4) * 8;
  const bf16* Wt = Wht + (size_t)e * NA * HID;

  __shared__ bf16 sA[BM * BK];
  __shared__ bf16 sB[BN * BK];
  f32x4 acc[4][4] = {};

  const bf16* pA = H + (size_t)(mb0 + (t >> 3)) * HID + (t & 7) * 8;
  const bf16* pB = Wt + (size_t)(bn0 + (t >> 3)) * HID + (t & 7) * 8;
  const size_t slotstride = (size_t)32 * HID;

  for (int k0 = 0; k0 < HID; k0 += BK) {
    __syncthreads();
#pragma unroll
    for (int s = 0; s < 4; ++s) {
      gload16(pA + s * slotstride, (char*)sA + s * 4096 + w * 1024);
      gload16(pB + s * slotstride, (char*)sB + s * 4096 + w * 1024);
    }
    pA += BK; pB += BK;
    __syncthreads();
#pragma unroll
    for (int kh = 0; kh < 2; ++kh) {
      FRAG_READS(sA, sB, kh)
#pragma unroll
      for (int m = 0; m < 4; ++m)
#pragma unroll
        for (int n = 0; n < 4; ++n)
          acc[m][n] = __builtin_amdgcn_mfma_f32_16x16x32_bf16(af[m], bfr[n], acc[m][n], 0, 0, 0);
    }
  }

#pragma unroll
  for (int m = 0; m < 4; ++m) {
#pragma unroll
    for (int r = 0; r < 4; ++r) {
      int ps = mb0 + wr * 64 + m * 16 + (l >> 4) * 4 + r;
      if (ps < pend) {
        int row = rowid[ps];
#pragma unroll
        for (int n = 0; n < 4; ++n) {
          int col = bn0 + wc * 64 + n * 16 + lr;
          float v = acc[m][n][r] + bh[e * NA + col];
          float sp = (v > 20.f) ? v : log1pf(expf(v));
          Out[(size_t)row * NA + col] = sp + 1.f;
        }
      }
    }
  }
}

// ---------------- launch ----------------
extern "C" void kernel_launch(void* const* d_in, const int* in_sizes, int n_in,
                              void* d_out, int out_size, void* d_ws, size_t ws_size,
                              hipStream_t stream) {
  const float* x  = (const float*)d_in[0];
  const float* W1 = (const float*)d_in[1];
  const float* b1 = (const float*)d_in[2];
  const float* W2 = (const float*)d_in[3];
  const float* b2 = (const float*)d_in[4];
  const float* Wh = (const float*)d_in[5];
  const float* bh = (const float*)d_in[6];
  float* out = (float*)d_out;

  // workspace carve (all 256B-aligned)
  char* p = (char*)d_ws;
  bf16* xb  = (bf16*)p; p += (size_t)PADM * INDIM * 2;  // 8.7 MiB (permuted)
  bf16* w1t = (bf16*)p; p += (size_t)HID * INDIM * 2;   // 512 KiB
  bf16* w2t = (bf16*)p; p += (size_t)HID * HID * 2;     // 2 MiB
  bf16* wht = (bf16*)p; p += (size_t)NE * NA * HID * 2; // 4 MiB
  bf16* h1b = (bf16*)p; p += (size_t)PADM * HID * 2;    // 34.6 MiB (permuted)
  bf16* h2b = (bf16*)p; p += (size_t)PADM * HID * 2;    // 34.6 MiB (permuted)
  int* sortidx = (int*)p; p += (size_t)BSZ * 4;         // orig -> padded pos
  int* rowid   = (int*)p; p += (size_t)PADM * 4;        // padded pos -> orig
  int* cnt    = (int*)p; p += 256;
  int* poff   = (int*)p; p += 256;
  int* cursor = (int*)p; p += 256;

  const int MB = PADM / BM;  // 132 m-blocks over padded row space

  // routing (counting sort of rows by regime, hierarchical histogram)
  k_zero<<<1, 64, 0, stream>>>(cnt, cursor);
  k_count<<<BSZ / 256, 256, 0, stream>>>(x, cnt);
  k_prefix<<<1, 64, 0, stream>>>(cnt, poff);
  k_scatter<<<BSZ / 256, 256, 0, stream>>>(x, poff, cursor, sortidx, rowid);

  // bf16 conversions (x cast lands in permuted row order)
  k_cast_perm<<<BSZ * (INDIM / 8) / 256, 256, 0, stream>>>(x, sortidx, xb);
  k_transpose<<<dim3(HID / 32, INDIM / 32, 1), dim3(32, 8), 0, stream>>>(W1, w1t, INDIM, HID);
  k_transpose<<<dim3(HID / 32, HID / 32, 1), dim3(32, 8), 0, stream>>>(W2, w2t, HID, HID);
  k_transpose<<<dim3(NA / 32, HID / 32, NE), dim3(32, 8), 0, stream>>>(Wh, wht, HID, NA);

  // GEMM1: h1 = relu(xs @ W1 + b1)   (padded rows compute garbage, masked later)
  k_gemm_relu<<<dim3(HID / BN, MB), 256, 0, stream>>>(xb, w1t, b1, h1b, HID, INDIM);
  // GEMM2: h2 = relu(h1 @ W2 + b2)
  k_gemm_relu<<<dim3(HID / BN, MB), 256, 0, stream>>>(h1b, w2t, b2, h2b, HID, HID);
  // GEMM3: dense per-head, softplus+1, scatter store via rowid
  k_gemm_head<<<dim3(NA / BN, MB), 256, 0, stream>>>(h2b, wht, bh, poff, cnt, rowid, out);
}

// Round 8
// 264.800 us; speedup vs baseline: 1.1018x; 1.0887x over previous
//
#include <hip/hip_runtime.h>
#include <hip/hip_bf16.h>
#include <stdint.h>

// Problem constants (from reference)
#define BSZ   16384
#define INDIM 256
#define HID   1024
#define NA    512
#define NE    4
#define BM 128
#define BN 128
#define BK 32
// padded-sorted row space: each head segment 128-aligned
#define PADM (BSZ + NE * BM)   // 16896

typedef __hip_bfloat16 bf16;
typedef __attribute__((ext_vector_type(8))) short    short8;
typedef __attribute__((ext_vector_type(4))) float    f32x4;
typedef __attribute__((ext_vector_type(8))) unsigned short u16x8;

// ---------------- async global->LDS (16B per lane) ----------------
// HW semantics: LDS dest = wave-uniform base + lane*16; global src is per-lane.
__device__ __forceinline__ void gload16(const void* g, void* l) {
  __builtin_amdgcn_global_load_lds(
      (__attribute__((address_space(1))) void*)g,
      (__attribute__((address_space(3))) void*)l, 16, 0, 0);
}

// ---------------- routing ----------------
__global__ void k_zero(int* cnt, int* cursor) {
  if (threadIdx.x < NE) { cnt[threadIdx.x] = 0; cursor[threadIdx.x] = 0; }
}

// per-block LDS histogram -> 4 global atomics per block
__global__ void k_count(const float* __restrict__ x, int* __restrict__ cnt) {
  __shared__ int h[NE];
  const int t = threadIdx.x;
  if (t < NE) h[t] = 0;
  __syncthreads();
  int i = blockIdx.x * blockDim.x + t;
  int r = (int)x[(size_t)i * INDIM + (INDIM - 1)];
  if (r >= 0 && r < NE) atomicAdd(&h[r], 1);
  __syncthreads();
  if (t < NE && h[t] > 0) atomicAdd(&cnt[t], h[t]);
}

// padded prefix: segment e starts at poff[e], size ceil(cnt/BM)*BM; poff[NE]=total
__global__ void k_prefix(const int* __restrict__ cnt, int* __restrict__ poff) {
  if (threadIdx.x == 0) {
    int a = 0;
    for (int e = 0; e < NE; ++e) {
      poff[e] = a;
      a += (cnt[e] + BM - 1) / BM * BM;
    }
    poff[NE] = a;
  }
}

// block claims contiguous chunk per regime; emits both directions of the perm
__global__ void k_scatter(const float* __restrict__ x, const int* __restrict__ poff,
                          int* __restrict__ cursor, int* __restrict__ sortidx,
                          int* __restrict__ rowid) {
  __shared__ int h[NE], base[NE];
  const int t = threadIdx.x;
  if (t < NE) h[t] = 0;
  __syncthreads();
  int i = blockIdx.x * blockDim.x + t;
  int r = (int)x[(size_t)i * INDIM + (INDIM - 1)];
  int lrank = -1;
  if (r >= 0 && r < NE) lrank = atomicAdd(&h[r], 1);
  __syncthreads();
  if (t < NE) base[t] = (h[t] > 0) ? atomicAdd(&cursor[t], h[t]) : 0;
  __syncthreads();
  if (r >= 0 && r < NE) {
    int p = poff[r] + base[r] + lrank;
    sortidx[i] = p;
    rowid[p] = i;
  }
}

// fp32 -> bf16 cast INTO PERMUTED ROW ORDER. 8 cols/thread; 32 consecutive
// threads share a row -> writes are contiguous 512B segments per row.
__global__ void k_cast_perm(const float* __restrict__ x, const int* __restrict__ sortidx,
                            bf16* __restrict__ xb) {
  int i = blockIdx.x * blockDim.x + threadIdx.x;   // [0, BSZ*INDIM/8)
  int row = i >> 5, c8 = (i & 31) * 8;
  int drow = sortidx[row];
  const float4* s = (const float4*)(x + (size_t)row * INDIM + c8);
  float4 a = s[0], b = s[1];
  bf16 t[8];
  t[0] = __float2bfloat16(a.x); t[1] = __float2bfloat16(a.y);
  t[2] = __float2bfloat16(a.z); t[3] = __float2bfloat16(a.w);
  t[4] = __float2bfloat16(b.x); t[5] = __float2bfloat16(b.y);
  t[6] = __float2bfloat16(b.z); t[7] = __float2bfloat16(b.w);
  *(u16x8*)(xb + (size_t)drow * INDIM + c8) = *(u16x8*)t;
}

// fp32 [R][C] -> bf16 [C][R], batched on z. grid(C/32, R/32, batch), block(32,8)
__global__ void k_transpose(const float* __restrict__ src, bf16* __restrict__ dst,
                            int R, int C) {
  __shared__ float tile[32][33];
  const float* s = src + (size_t)blockIdx.z * R * C;
  bf16* d = dst + (size_t)blockIdx.z * R * C;
  int c0 = blockIdx.x * 32, r0 = blockIdx.y * 32;
  int tx = threadIdx.x, ty = threadIdx.y;
#pragma unroll
  for (int i = 0; i < 32; i += 8)
    tile[ty + i][tx] = s[(size_t)(r0 + ty + i) * C + c0 + tx];
  __syncthreads();
#pragma unroll
  for (int i = 0; i < 32; i += 8)
    d[(size_t)(c0 + ty + i) * R + r0 + tx] = __float2bfloat16(tile[tx][ty + i]);
}

// ---------------- GEMM core macros (BK=32, counted-vmcnt dbuf pipeline) -------
// Stage one 128x32 A-tile + B-tile: 4 gload16/thread (2 A-slots, 2 B-slots of
// 64 rows each). Thread t -> row (t>>2) in slot, 16B chunk (t&3).
#define STAGE(pa, pb, sa, sb, KK)                                       \
  { _Pragma("unroll")                                                   \
    for (int s = 0; s < 2; ++s) {                                       \
      gload16((pa) + (size_t)s * 64 * (KK), (char*)(sa) + s * 4096 + w * 1024); \
      gload16((pb) + (size_t)s * 64 * (KK), (char*)(sb) + s * 4096 + w * 1024); \
    } }

#define COMPUTE(sa, sb)                                                 \
  { short8 af[4], bfr[4];                                               \
    _Pragma("unroll")                                                   \
    for (int m = 0; m < 4; ++m)                                         \
      af[m] = *(const short8*)&(sa)[(wr * 64 + m * 16 + lr) * BK + lk]; \
    _Pragma("unroll")                                                   \
    for (int n = 0; n < 4; ++n)                                         \
      bfr[n] = *(const short8*)&(sb)[(wc * 64 + n * 16 + lr) * BK + lk];\
    _Pragma("unroll")                                                   \
    for (int m = 0; m < 4; ++m)                                         \
      _Pragma("unroll")                                                 \
      for (int n = 0; n < 4; ++n)                                       \
        acc[m][n] = __builtin_amdgcn_mfma_f32_16x16x32_bf16(af[m], bfr[n], acc[m][n], 0, 0, 0); }

// Pipeline: stage(next) BEFORE computing current; counted vmcnt(4) certifies
// only the CURRENT tile's 4 loads (FIFO), next tile's stay in flight across
// the raw barrier. Second barrier protects the buffer from next overwrite.
#define KLOOP(pa, pb, KK)                                               \
  STAGE(pa, pb, sA[0], sB[0], KK); (pa) += BK; (pb) += BK;              \
  _Pragma("unroll 2")                                                   \
  for (int kt = 0; kt < (KK) / BK; ++kt) {                              \
    if (kt + 1 < (KK) / BK) {                                           \
      STAGE(pa, pb, sA[(kt + 1) & 1], sB[(kt + 1) & 1], KK);            \
      (pa) += BK; (pb) += BK;                                           \
      asm volatile("s_waitcnt vmcnt(4)" ::: "memory");                  \
    } else {                                                            \
      asm volatile("s_waitcnt vmcnt(0)" ::: "memory");                  \
    }                                                                   \
    __builtin_amdgcn_sched_barrier(0);                                  \
    __builtin_amdgcn_s_barrier();                                       \
    COMPUTE(sA[kt & 1], sB[kt & 1]);                                    \
    __builtin_amdgcn_s_barrier();                                       \
  }

// ---------------- GEMM: C = relu(A @ Bt^T + bias) -> bf16 ----------------
template <int K>
__global__ __launch_bounds__(256) void k_gemm_relu(
    const bf16* __restrict__ A, const bf16* __restrict__ Bt,
    const float* __restrict__ bias, bf16* __restrict__ Out, int N) {
  __shared__ bf16 sA[2][BM * BK];   // 2 x 8 KiB
  __shared__ bf16 sB[2][BN * BK];
  const int t = threadIdx.x, w = t >> 6, l = t & 63;
  const int wr = w >> 1, wc = w & 1;
  const int bm0 = blockIdx.y * BM, bn0 = blockIdx.x * BN;
  const int lr = l & 15, lk = (l >> 4) * 8;
  f32x4 acc[4][4] = {};

  const bf16* pA = A + (size_t)(bm0 + (t >> 2)) * K + (t & 3) * 8;
  const bf16* pB = Bt + (size_t)(bn0 + (t >> 2)) * K + (t & 3) * 8;
  KLOOP(pA, pB, K)

#pragma unroll
  for (int m = 0; m < 4; ++m) {
#pragma unroll
    for (int n = 0; n < 4; ++n) {
      int col = bn0 + wc * 64 + n * 16 + lr;
      float bv = bias[col];
#pragma unroll
      for (int r = 0; r < 4; ++r) {
        int row = bm0 + wr * 64 + m * 16 + (l >> 4) * 4 + r;
        float v = acc[m][n][r] + bv;
        v = v > 0.f ? v : 0.f;
        Out[(size_t)row * N + col] = __float2bfloat16(v);
      }
    }
  }
}

// ---------------- GEMM3: dense per-head GEMM on padded-sorted rows ----------------
// grid (NA/BN=4, PADM/BM=132). Head from poff; softplus+1; scatter store.
__global__ __launch_bounds__(256) void k_gemm_head(
    const bf16* __restrict__ H,      // [PADM][HID] padded-sorted
    const bf16* __restrict__ Wht,    // [NE][NA][HID]
    const float* __restrict__ bh,    // [NE][NA]
    const int* __restrict__ poff,    // [NE+1]
    const int* __restrict__ cnt,     // [NE]
    const int* __restrict__ rowid,   // [PADM]
    float* __restrict__ Out) {
  const int mb0 = blockIdx.y * BM;
  if (mb0 >= poff[NE]) return;   // block-uniform exit (before any barrier)
  int e = 0;
#pragma unroll
  for (int k = 1; k < NE; ++k) if (mb0 >= poff[k]) e = k;
  const int pend = poff[e] + cnt[e];   // rows >= pend are padding

  const int t = threadIdx.x, w = t >> 6, l = t & 63;
  const int wr = w >> 1, wc = w & 1;
  const int bn0 = blockIdx.x * BN;
  const int lr = l & 15, lk = (l >> 4) * 8;
  const bf16* Wt = Wht + (size_t)e * NA * HID;

  __shared__ bf16 sA[2][BM * BK];
  __shared__ bf16 sB[2][BN * BK];
  f32x4 acc[4][4] = {};

  const bf16* pA = H + (size_t)(mb0 + (t >> 2)) * HID + (t & 3) * 8;
  const bf16* pB = Wt + (size_t)(bn0 + (t >> 2)) * HID + (t & 3) * 8;
  KLOOP(pA, pB, HID)

#pragma unroll
  for (int m = 0; m < 4; ++m) {
#pragma unroll
    for (int r = 0; r < 4; ++r) {
      int ps = mb0 + wr * 64 + m * 16 + (l >> 4) * 4 + r;
      if (ps < pend) {
        int row = rowid[ps];
#pragma unroll
        for (int n = 0; n < 4; ++n) {
          int col = bn0 + wc * 64 + n * 16 + lr;
          float v = acc[m][n][r] + bh[e * NA + col];
          float sp = (v > 20.f) ? v : log1pf(expf(v));
          Out[(size_t)row * NA + col] = sp + 1.f;
        }
      }
    }
  }
}

// ---------------- launch ----------------
extern "C" void kernel_launch(void* const* d_in, const int* in_sizes, int n_in,
                              void* d_out, int out_size, void* d_ws, size_t ws_size,
                              hipStream_t stream) {
  const float* x  = (const float*)d_in[0];
  const float* W1 = (const float*)d_in[1];
  const float* b1 = (const float*)d_in[2];
  const float* W2 = (const float*)d_in[3];
  const float* b2 = (const float*)d_in[4];
  const float* Wh = (const float*)d_in[5];
  const float* bh = (const float*)d_in[6];
  float* out = (float*)d_out;

  // workspace carve (all 256B-aligned)
  char* p = (char*)d_ws;
  bf16* xb  = (bf16*)p; p += (size_t)PADM * INDIM * 2;  // 8.7 MiB (permuted)
  bf16* w1t = (bf16*)p; p += (size_t)HID * INDIM * 2;   // 512 KiB
  bf16* w2t = (bf16*)p; p += (size_t)HID * HID * 2;     // 2 MiB
  bf16* wht = (bf16*)p; p += (size_t)NE * NA * HID * 2; // 4 MiB
  bf16* h1b = (bf16*)p; p += (size_t)PADM * HID * 2;    // 34.6 MiB (permuted)
  bf16* h2b = (bf16*)p; p += (size_t)PADM * HID * 2;    // 34.6 MiB (permuted)
  int* sortidx = (int*)p; p += (size_t)BSZ * 4;         // orig -> padded pos
  int* rowid   = (int*)p; p += (size_t)PADM * 4;        // padded pos -> orig
  int* cnt    = (int*)p; p += 256;
  int* poff   = (int*)p; p += 256;
  int* cursor = (int*)p; p += 256;

  const int MB = PADM / BM;  // 132 m-blocks over padded row space

  // routing (counting sort of rows by regime, hierarchical histogram)
  k_zero<<<1, 64, 0, stream>>>(cnt, cursor);
  k_count<<<BSZ / 256, 256, 0, stream>>>(x, cnt);
  k_prefix<<<1, 64, 0, stream>>>(cnt, poff);
  k_scatter<<<BSZ / 256, 256, 0, stream>>>(x, poff, cursor, sortidx, rowid);

  // bf16 conversions (x cast lands in permuted row order)
  k_cast_perm<<<BSZ * (INDIM / 8) / 256, 256, 0, stream>>>(x, sortidx, xb);
  k_transpose<<<dim3(HID / 32, INDIM / 32, 1), dim3(32, 8), 0, stream>>>(W1, w1t, INDIM, HID);
  k_transpose<<<dim3(HID / 32, HID / 32, 1), dim3(32, 8), 0, stream>>>(W2, w2t, HID, HID);
  k_transpose<<<dim3(NA / 32, HID / 32, NE), dim3(32, 8), 0, stream>>>(Wh, wht, HID, NA);

  // GEMM1: h1 = relu(xs @ W1 + b1)   (padded rows compute garbage, masked later)
  k_gemm_relu<INDIM><<<dim3(HID / BN, MB), 256, 0, stream>>>(xb, w1t, b1, h1b, HID);
  // GEMM2: h2 = relu(h1 @ W2 + b2)
  k_gemm_relu<HID><<<dim3(HID / BN, MB), 256, 0, stream>>>(h1b, w2t, b2, h2b, HID);
  // GEMM3: dense per-head, softplus+1, scatter store via rowid
  k_gemm_head<<<dim3(NA / BN, MB), 256, 0, stream>>>(h2b, wht, bh, poff, cnt, rowid, out);
}

// Round 9
// 264.507 us; speedup vs baseline: 1.1030x; 1.0011x over previous
//
#include <hip/hip_runtime.h>
#include <hip/hip_bf16.h>
#include <stdint.h>

// Problem constants (from reference)
#define BSZ   16384
#define INDIM 256
#define HID   1024
#define NA    512
#define NE    4
#define BM 128
#define BN 128
#define BNH 64      // gemm_head N-tile: doubles grid to 1056 blocks (TLP fix)
#define BK 32
// padded-sorted row space: each head segment 128-aligned
#define PADM (BSZ + NE * BM)   // 16896

typedef __hip_bfloat16 bf16;
typedef __attribute__((ext_vector_type(8))) short    short8;
typedef __attribute__((ext_vector_type(4))) float    f32x4;
typedef __attribute__((ext_vector_type(8))) unsigned short u16x8;

// ---------------- async global->LDS (16B per lane) ----------------
// HW semantics: LDS dest = wave-uniform base + lane*16; global src is per-lane.
__device__ __forceinline__ void gload16(const void* g, void* l) {
  __builtin_amdgcn_global_load_lds(
      (__attribute__((address_space(1))) void*)g,
      (__attribute__((address_space(3))) void*)l, 16, 0, 0);
}

// ---------------- routing ----------------
__global__ void k_zero(int* cnt, int* cursor) {
  if (threadIdx.x < NE) { cnt[threadIdx.x] = 0; cursor[threadIdx.x] = 0; }
}

// per-block LDS histogram -> 4 global atomics per block
__global__ void k_count(const float* __restrict__ x, int* __restrict__ cnt) {
  __shared__ int h[NE];
  const int t = threadIdx.x;
  if (t < NE) h[t] = 0;
  __syncthreads();
  int i = blockIdx.x * blockDim.x + t;
  int r = (int)x[(size_t)i * INDIM + (INDIM - 1)];
  if (r >= 0 && r < NE) atomicAdd(&h[r], 1);
  __syncthreads();
  if (t < NE && h[t] > 0) atomicAdd(&cnt[t], h[t]);
}

// padded prefix: segment e starts at poff[e], size ceil(cnt/BM)*BM; poff[NE]=total
__global__ void k_prefix(const int* __restrict__ cnt, int* __restrict__ poff) {
  if (threadIdx.x == 0) {
    int a = 0;
    for (int e = 0; e < NE; ++e) {
      poff[e] = a;
      a += (cnt[e] + BM - 1) / BM * BM;
    }
    poff[NE] = a;
  }
}

// block claims contiguous chunk per regime; emits both directions of the perm
__global__ void k_scatter(const float* __restrict__ x, const int* __restrict__ poff,
                          int* __restrict__ cursor, int* __restrict__ sortidx,
                          int* __restrict__ rowid) {
  __shared__ int h[NE], base[NE];
  const int t = threadIdx.x;
  if (t < NE) h[t] = 0;
  __syncthreads();
  int i = blockIdx.x * blockDim.x + t;
  int r = (int)x[(size_t)i * INDIM + (INDIM - 1)];
  int lrank = -1;
  if (r >= 0 && r < NE) lrank = atomicAdd(&h[r], 1);
  __syncthreads();
  if (t < NE) base[t] = (h[t] > 0) ? atomicAdd(&cursor[t], h[t]) : 0;
  __syncthreads();
  if (r >= 0 && r < NE) {
    int p = poff[r] + base[r] + lrank;
    sortidx[i] = p;
    rowid[p] = i;
  }
}

// fp32 -> bf16 cast INTO PERMUTED ROW ORDER. 8 cols/thread; 32 consecutive
// threads share a row -> writes are contiguous 512B segments per row.
__global__ void k_cast_perm(const float* __restrict__ x, const int* __restrict__ sortidx,
                            bf16* __restrict__ xb) {
  int i = blockIdx.x * blockDim.x + threadIdx.x;   // [0, BSZ*INDIM/8)
  int row = i >> 5, c8 = (i & 31) * 8;
  int drow = sortidx[row];
  const float4* s = (const float4*)(x + (size_t)row * INDIM + c8);
  float4 a = s[0], b = s[1];
  bf16 t[8];
  t[0] = __float2bfloat16(a.x); t[1] = __float2bfloat16(a.y);
  t[2] = __float2bfloat16(a.z); t[3] = __float2bfloat16(a.w);
  t[4] = __float2bfloat16(b.x); t[5] = __float2bfloat16(b.y);
  t[6] = __float2bfloat16(b.z); t[7] = __float2bfloat16(b.w);
  *(u16x8*)(xb + (size_t)drow * INDIM + c8) = *(u16x8*)t;
}

// fp32 [R][C] -> bf16 [C][R], batched on z. grid(C/32, R/32, batch), block(32,8)
__global__ void k_transpose(const float* __restrict__ src, bf16* __restrict__ dst,
                            int R, int C) {
  __shared__ float tile[32][33];
  const float* s = src + (size_t)blockIdx.z * R * C;
  bf16* d = dst + (size_t)blockIdx.z * R * C;
  int c0 = blockIdx.x * 32, r0 = blockIdx.y * 32;
  int tx = threadIdx.x, ty = threadIdx.y;
#pragma unroll
  for (int i = 0; i < 32; i += 8)
    tile[ty + i][tx] = s[(size_t)(r0 + ty + i) * C + c0 + tx];
  __syncthreads();
#pragma unroll
  for (int i = 0; i < 32; i += 8)
    d[(size_t)(c0 + ty + i) * R + r0 + tx] = __float2bfloat16(tile[tx][ty + i]);
}

// ---------------- GEMM core macros (BK=32, counted-vmcnt dbuf pipeline) -------
// Stage one 128x32 A-tile + 128x32 B-tile: 4 gload16/thread.
#define STAGE(pa, pb, sa, sb, KK)                                       \
  { _Pragma("unroll")                                                   \
    for (int s = 0; s < 2; ++s) {                                       \
      gload16((pa) + (size_t)s * 64 * (KK), (char*)(sa) + s * 4096 + w * 1024); \
      gload16((pb) + (size_t)s * 64 * (KK), (char*)(sb) + s * 4096 + w * 1024); \
    } }

#define COMPUTE(sa, sb)                                                 \
  { short8 af[4], bfr[4];                                               \
    _Pragma("unroll")                                                   \
    for (int m = 0; m < 4; ++m)                                         \
      af[m] = *(const short8*)&(sa)[(wr * 64 + m * 16 + lr) * BK + lk]; \
    _Pragma("unroll")                                                   \
    for (int n = 0; n < 4; ++n)                                         \
      bfr[n] = *(const short8*)&(sb)[(wc * 64 + n * 16 + lr) * BK + lk];\
    _Pragma("unroll")                                                   \
    for (int m = 0; m < 4; ++m)                                         \
      _Pragma("unroll")                                                 \
      for (int n = 0; n < 4; ++n)                                       \
        acc[m][n] = __builtin_amdgcn_mfma_f32_16x16x32_bf16(af[m], bfr[n], acc[m][n], 0, 0, 0); }

// Pipeline: stage(next) BEFORE computing current; counted vmcnt certifies only
// the CURRENT tile's loads (FIFO), next tile's stay in flight across barrier.
#define KLOOP(pa, pb, KK)                                               \
  STAGE(pa, pb, sA[0], sB[0], KK); (pa) += BK; (pb) += BK;              \
  _Pragma("unroll 2")                                                   \
  for (int kt = 0; kt < (KK) / BK; ++kt) {                              \
    if (kt + 1 < (KK) / BK) {                                           \
      STAGE(pa, pb, sA[(kt + 1) & 1], sB[(kt + 1) & 1], KK);            \
      (pa) += BK; (pb) += BK;                                           \
      asm volatile("s_waitcnt vmcnt(4)" ::: "memory");                  \
    } else {                                                            \
      asm volatile("s_waitcnt vmcnt(0)" ::: "memory");                  \
    }                                                                   \
    __builtin_amdgcn_sched_barrier(0);                                  \
    __builtin_amdgcn_s_barrier();                                       \
    COMPUTE(sA[kt & 1], sB[kt & 1]);                                    \
    __builtin_amdgcn_s_barrier();                                       \
  }

// ---- head variants: A 128 rows (2 slots), B 64 rows (1 slot), 3 loads/thread
#define STAGE_H(pa, pb, sa, sb, KK)                                     \
  { _Pragma("unroll")                                                   \
    for (int s = 0; s < 2; ++s)                                         \
      gload16((pa) + (size_t)s * 64 * (KK), (char*)(sa) + s * 4096 + w * 1024); \
    gload16((pb), (char*)(sb) + w * 1024); }

#define COMPUTE_H(sa, sb)                                               \
  { short8 af[4], bfr[2];                                               \
    _Pragma("unroll")                                                   \
    for (int m = 0; m < 4; ++m)                                         \
      af[m] = *(const short8*)&(sa)[(wr * 64 + m * 16 + lr) * BK + lk]; \
    _Pragma("unroll")                                                   \
    for (int n = 0; n < 2; ++n)                                         \
      bfr[n] = *(const short8*)&(sb)[(wc * 32 + n * 16 + lr) * BK + lk];\
    _Pragma("unroll")                                                   \
    for (int m = 0; m < 4; ++m)                                         \
      _Pragma("unroll")                                                 \
      for (int n = 0; n < 2; ++n)                                       \
        acc[m][n] = __builtin_amdgcn_mfma_f32_16x16x32_bf16(af[m], bfr[n], acc[m][n], 0, 0, 0); }

#define KLOOP_H(pa, pb, KK)                                             \
  STAGE_H(pa, pb, sA[0], sB[0], KK); (pa) += BK; (pb) += BK;            \
  _Pragma("unroll 2")                                                   \
  for (int kt = 0; kt < (KK) / BK; ++kt) {                              \
    if (kt + 1 < (KK) / BK) {                                           \
      STAGE_H(pa, pb, sA[(kt + 1) & 1], sB[(kt + 1) & 1], KK);          \
      (pa) += BK; (pb) += BK;                                           \
      asm volatile("s_waitcnt vmcnt(3)" ::: "memory");                  \
    } else {                                                            \
      asm volatile("s_waitcnt vmcnt(0)" ::: "memory");                  \
    }                                                                   \
    __builtin_amdgcn_sched_barrier(0);                                  \
    __builtin_amdgcn_s_barrier();                                       \
    COMPUTE_H(sA[kt & 1], sB[kt & 1]);                                  \
    __builtin_amdgcn_s_barrier();                                       \
  }

// ---------------- GEMM: C = relu(A @ Bt^T + bias) -> bf16 ----------------
template <int K>
__global__ __launch_bounds__(256) void k_gemm_relu(
    const bf16* __restrict__ A, const bf16* __restrict__ Bt,
    const float* __restrict__ bias, bf16* __restrict__ Out, int N) {
  __shared__ bf16 sA[2][BM * BK];   // 2 x 8 KiB
  __shared__ bf16 sB[2][BN * BK];
  const int t = threadIdx.x, w = t >> 6, l = t & 63;
  const int wr = w >> 1, wc = w & 1;
  const int bm0 = blockIdx.y * BM, bn0 = blockIdx.x * BN;
  const int lr = l & 15, lk = (l >> 4) * 8;
  f32x4 acc[4][4] = {};

  const bf16* pA = A + (size_t)(bm0 + (t >> 2)) * K + (t & 3) * 8;
  const bf16* pB = Bt + (size_t)(bn0 + (t >> 2)) * K + (t & 3) * 8;
  KLOOP(pA, pB, K)

#pragma unroll
  for (int m = 0; m < 4; ++m) {
#pragma unroll
    for (int n = 0; n < 4; ++n) {
      int col = bn0 + wc * 64 + n * 16 + lr;
      float bv = bias[col];
#pragma unroll
      for (int r = 0; r < 4; ++r) {
        int row = bm0 + wr * 64 + m * 16 + (l >> 4) * 4 + r;
        float v = acc[m][n][r] + bv;
        v = v > 0.f ? v : 0.f;
        Out[(size_t)row * N + col] = __float2bfloat16(v);
      }
    }
  }
}

// ---------------- GEMM3: dense per-head GEMM on padded-sorted rows ----------------
// 128x64 tile -> grid (NA/BNH=8, PADM/BM=132) = 1056 blocks (~4.1/CU, TLP fix).
// Head from poff; softplus+1; scatter store via rowid.
__global__ __launch_bounds__(256) void k_gemm_head(
    const bf16* __restrict__ H,      // [PADM][HID] padded-sorted
    const bf16* __restrict__ Wht,    // [NE][NA][HID]
    const float* __restrict__ bh,    // [NE][NA]
    const int* __restrict__ poff,    // [NE+1]
    const int* __restrict__ cnt,     // [NE]
    const int* __restrict__ rowid,   // [PADM]
    float* __restrict__ Out) {
  const int mb0 = blockIdx.y * BM;
  if (mb0 >= poff[NE]) return;   // block-uniform exit (before any barrier)
  int e = 0;
#pragma unroll
  for (int k = 1; k < NE; ++k) if (mb0 >= poff[k]) e = k;
  const int pend = poff[e] + cnt[e];   // rows >= pend are padding

  const int t = threadIdx.x, w = t >> 6, l = t & 63;
  const int wr = w >> 1, wc = w & 1;
  const int bn0 = blockIdx.x * BNH;
  const int lr = l & 15, lk = (l >> 4) * 8;
  const bf16* Wt = Wht + (size_t)e * NA * HID;

  __shared__ bf16 sA[2][BM * BK];    // 2 x 8 KiB
  __shared__ bf16 sB[2][BNH * BK];   // 2 x 4 KiB
  f32x4 acc[4][2] = {};

  const bf16* pA = H + (size_t)(mb0 + (t >> 2)) * HID + (t & 3) * 8;
  const bf16* pB = Wt + (size_t)(bn0 + (t >> 2)) * HID + (t & 3) * 8;
  KLOOP_H(pA, pB, HID)

#pragma unroll
  for (int m = 0; m < 4; ++m) {
#pragma unroll
    for (int r = 0; r < 4; ++r) {
      int ps = mb0 + wr * 64 + m * 16 + (l >> 4) * 4 + r;
      if (ps < pend) {
        int row = rowid[ps];
#pragma unroll
        for (int n = 0; n < 2; ++n) {
          int col = bn0 + wc * 32 + n * 16 + lr;
          float v = acc[m][n][r] + bh[e * NA + col];
          float sp = (v > 20.f) ? v : log1pf(expf(v));
          Out[(size_t)row * NA + col] = sp + 1.f;
        }
      }
    }
  }
}

// ---------------- launch ----------------
extern "C" void kernel_launch(void* const* d_in, const int* in_sizes, int n_in,
                              void* d_out, int out_size, void* d_ws, size_t ws_size,
                              hipStream_t stream) {
  const float* x  = (const float*)d_in[0];
  const float* W1 = (const float*)d_in[1];
  const float* b1 = (const float*)d_in[2];
  const float* W2 = (const float*)d_in[3];
  const float* b2 = (const float*)d_in[4];
  const float* Wh = (const float*)d_in[5];
  const float* bh = (const float*)d_in[6];
  float* out = (float*)d_out;

  // workspace carve (all 256B-aligned)
  char* p = (char*)d_ws;
  bf16* xb  = (bf16*)p; p += (size_t)PADM * INDIM * 2;  // 8.7 MiB (permuted)
  bf16* w1t = (bf16*)p; p += (size_t)HID * INDIM * 2;   // 512 KiB
  bf16* w2t = (bf16*)p; p += (size_t)HID * HID * 2;     // 2 MiB
  bf16* wht = (bf16*)p; p += (size_t)NE * NA * HID * 2; // 4 MiB
  bf16* h1b = (bf16*)p; p += (size_t)PADM * HID * 2;    // 34.6 MiB (permuted)
  bf16* h2b = (bf16*)p; p += (size_t)PADM * HID * 2;    // 34.6 MiB (permuted)
  int* sortidx = (int*)p; p += (size_t)BSZ * 4;         // orig -> padded pos
  int* rowid   = (int*)p; p += (size_t)PADM * 4;        // padded pos -> orig
  int* cnt    = (int*)p; p += 256;
  int* poff   = (int*)p; p += 256;
  int* cursor = (int*)p; p += 256;

  const int MB = PADM / BM;  // 132 m-blocks over padded row space

  // routing (counting sort of rows by regime, hierarchical histogram)
  k_zero<<<1, 64, 0, stream>>>(cnt, cursor);
  k_count<<<BSZ / 256, 256, 0, stream>>>(x, cnt);
  k_prefix<<<1, 64, 0, stream>>>(cnt, poff);
  k_scatter<<<BSZ / 256, 256, 0, stream>>>(x, poff, cursor, sortidx, rowid);

  // bf16 conversions (x cast lands in permuted row order)
  k_cast_perm<<<BSZ * (INDIM / 8) / 256, 256, 0, stream>>>(x, sortidx, xb);
  k_transpose<<<dim3(HID / 32, INDIM / 32, 1), dim3(32, 8), 0, stream>>>(W1, w1t, INDIM, HID);
  k_transpose<<<dim3(HID / 32, HID / 32, 1), dim3(32, 8), 0, stream>>>(W2, w2t, HID, HID);
  k_transpose<<<dim3(NA / 32, HID / 32, NE), dim3(32, 8), 0, stream>>>(Wh, wht, HID, NA);

  // GEMM1: h1 = relu(xs @ W1 + b1)   (padded rows compute garbage, masked later)
  k_gemm_relu<INDIM><<<dim3(HID / BN, MB), 256, 0, stream>>>(xb, w1t, b1, h1b, HID);
  // GEMM2: h2 = relu(h1 @ W2 + b2)
  k_gemm_relu<HID><<<dim3(HID / BN, MB), 256, 0, stream>>>(h1b, w2t, b2, h2b, HID);
  // GEMM3: dense per-head, softplus+1, scatter store via rowid
  k_gemm_head<<<dim3(NA / BNH, MB), 256, 0, stream>>>(h2b, wht, bh, poff, cnt, rowid, out);
}

// Round 11
// 252.832 us; speedup vs baseline: 1.1540x; 1.0462x over previous
//
#include <hip/hip_runtime.h>
#include <hip/hip_bf16.h>
#include <stdint.h>

// Problem constants (from reference)
#define BSZ   16384
#define INDIM 256
#define HID   1024
#define NA    512
#define NE    4
#define BM 128
#define BN 128
#define BK 32
// padded-sorted row space: each head segment 128-aligned
#define PADM (BSZ + NE * BM)   // 16896

typedef __hip_bfloat16 bf16;
typedef __attribute__((ext_vector_type(8))) short    short8;
typedef __attribute__((ext_vector_type(4))) float    f32x4;
typedef __attribute__((ext_vector_type(8))) unsigned short u16x8;

// ---------------- async global->LDS (16B per lane) ----------------
// HW semantics: LDS dest = wave-uniform base + lane*16; global src is per-lane.
__device__ __forceinline__ void gload16(const void* g, void* l) {
  __builtin_amdgcn_global_load_lds(
      (__attribute__((address_space(1))) void*)g,
      (__attribute__((address_space(3))) void*)l, 16, 0, 0);
}

// ---------------- routing ----------------
__global__ void k_zero(int* cnt, int* cursor) {
  if (threadIdx.x < NE) { cnt[threadIdx.x] = 0; cursor[threadIdx.x] = 0; }
}

// per-block LDS histogram -> 4 global atomics per block
__global__ void k_count(const float* __restrict__ x, int* __restrict__ cnt) {
  __shared__ int h[NE];
  const int t = threadIdx.x;
  if (t < NE) h[t] = 0;
  __syncthreads();
  int i = blockIdx.x * blockDim.x + t;
  int r = (int)x[(size_t)i * INDIM + (INDIM - 1)];
  if (r >= 0 && r < NE) atomicAdd(&h[r], 1);
  __syncthreads();
  if (t < NE && h[t] > 0) atomicAdd(&cnt[t], h[t]);
}

// padded prefix: segment e starts at poff[e], size ceil(cnt/BM)*BM; poff[NE]=total
__global__ void k_prefix(const int* __restrict__ cnt, int* __restrict__ poff) {
  if (threadIdx.x == 0) {
    int a = 0;
    for (int e = 0; e < NE; ++e) {
      poff[e] = a;
      a += (cnt[e] + BM - 1) / BM * BM;
    }
    poff[NE] = a;
  }
}

// block claims contiguous chunk per regime; emits both directions of the perm
__global__ void k_scatter(const float* __restrict__ x, const int* __restrict__ poff,
                          int* __restrict__ cursor, int* __restrict__ sortidx,
                          int* __restrict__ rowid) {
  __shared__ int h[NE], base[NE];
  const int t = threadIdx.x;
  if (t < NE) h[t] = 0;
  __syncthreads();
  int i = blockIdx.x * blockDim.x + t;
  int r = (int)x[(size_t)i * INDIM + (INDIM - 1)];
  int lrank = -1;
  if (r >= 0 && r < NE) lrank = atomicAdd(&h[r], 1);
  __syncthreads();
  if (t < NE) base[t] = (h[t] > 0) ? atomicAdd(&cursor[t], h[t]) : 0;
  __syncthreads();
  if (r >= 0 && r < NE) {
    int p = poff[r] + base[r] + lrank;
    sortidx[i] = p;
    rowid[p] = i;
  }
}

// fp32 -> bf16 cast INTO PERMUTED ROW ORDER. 8 cols/thread; 32 consecutive
// threads share a row -> writes are contiguous 512B segments per row.
__global__ void k_cast_perm(const float* __restrict__ x, const int* __restrict__ sortidx,
                            bf16* __restrict__ xb) {
  int i = blockIdx.x * blockDim.x + threadIdx.x;   // [0, BSZ*INDIM/8)
  int row = i >> 5, c8 = (i & 31) * 8;
  int drow = sortidx[row];
  const float4* s = (const float4*)(x + (size_t)row * INDIM + c8);
  float4 a = s[0], b = s[1];
  bf16 t[8];
  t[0] = __float2bfloat16(a.x); t[1] = __float2bfloat16(a.y);
  t[2] = __float2bfloat16(a.z); t[3] = __float2bfloat16(a.w);
  t[4] = __float2bfloat16(b.x); t[5] = __float2bfloat16(b.y);
  t[6] = __float2bfloat16(b.z); t[7] = __float2bfloat16(b.w);
  *(u16x8*)(xb + (size_t)drow * INDIM + c8) = *(u16x8*)t;
}

// fp32 [R][C] -> bf16 [C][R], batched on z. grid(C/32, R/32, batch), block(32,8)
__global__ void k_transpose(const float* __restrict__ src, bf16* __restrict__ dst,
                            int R, int C) {
  __shared__ float tile[32][33];
  const float* s = src + (size_t)blockIdx.z * R * C;
  bf16* d = dst + (size_t)blockIdx.z * R * C;
  int c0 = blockIdx.x * 32, r0 = blockIdx.y * 32;
  int tx = threadIdx.x, ty = threadIdx.y;
#pragma unroll
  for (int i = 0; i < 32; i += 8)
    tile[ty + i][tx] = s[(size_t)(r0 + ty + i) * C + c0 + tx];
  __syncthreads();
#pragma unroll
  for (int i = 0; i < 32; i += 8)
    d[(size_t)(c0 + ty + i) * R + r0 + tx] = __float2bfloat16(tile[tx][ty + i]);
}

// =================== GEMM core: triple-buffered 2-phase pipeline ===============
// LDS ring of 3 K-tile buffers (16 KB each: A 128x32 @ +0, B 128x32 @ +8192).
// While computing kt from buf[kt%3], stage kt+2 into buf[(kt+2)%3] — its
// readers (kt-1) finished before the barrier at end of kt-1, so no race and
// only ONE barrier per K-tile. Steady-state s_waitcnt vmcnt(4): the 4 stage
// instructions of kt+2 stay in flight across the barrier (T3+T4, never 0).
// Thread t stages row (t>>2), 16B chunk (t&3) of each 64-row unit (t*16 = its
// linear LDS byte -> matches gload_lds's base+lane*16 contiguity requirement).

// read one A fragment (m) and one B fragment (n) from a K-tile buffer
#define AFRAG(cur, m) (*(const short8*)((cur) + (wr * 64 + (m)*16 + lr) * 64 + (l >> 4) * 16))
#define BFRAG(cur, n) (*(const short8*)((cur) + 8192 + (wc * 64 + (n)*16 + lr) * 64 + (l >> 4) * 16))

#define STAGE_KT(pa, pb, dst, KK)                                   \
  { gload16((pa), (dst) + w * 1024);                                \
    gload16((pa) + (size_t)64 * (KK), (dst) + 4096 + w * 1024);     \
    gload16((pb), (dst) + 8192 + w * 1024);                         \
    gload16((pb) + (size_t)64 * (KK), (dst) + 12288 + w * 1024); }

#define KLOOP3(pa, pb, KK)                                                     \
  {                                                                            \
    char* cur = ldsbuf;                                                        \
    char* nxt = ldsbuf + 16384;                                                \
    char* stg = ldsbuf + 32768;                                                \
    STAGE_KT(pa, pb, cur, KK); (pa) += BK; (pb) += BK;                         \
    STAGE_KT(pa, pb, nxt, KK); (pa) += BK; (pb) += BK;                         \
    asm volatile("s_waitcnt vmcnt(4)" ::: "memory");                           \
    __builtin_amdgcn_s_barrier();                                              \
    const int NT = (KK) / BK;                                                  \
    for (int kt = 0; kt < NT; ++kt) {                                          \
      const bool more = (kt + 2 < NT);                                         \
      /* phase 0: A m0,m1 + B n0..3; stage kt+2's A-units */                   \
      short8 a0 = AFRAG(cur, 0), a1 = AFRAG(cur, 1);                           \
      short8 b0 = BFRAG(cur, 0), b1 = BFRAG(cur, 1);                           \
      short8 b2 = BFRAG(cur, 2), b3 = BFRAG(cur, 3);                           \
      if (more) {                                                              \
        gload16((pa), stg + w * 1024);                                         \
        gload16((pa) + (size_t)64 * (KK), stg + 4096 + w * 1024);              \
      }                                                                        \
      asm volatile("s_waitcnt lgkmcnt(0)" ::: "memory");                       \
      __builtin_amdgcn_sched_barrier(0);                                       \
      __builtin_amdgcn_s_setprio(1);                                           \
      acc[0][0] = __builtin_amdgcn_mfma_f32_16x16x32_bf16(a0, b0, acc[0][0], 0, 0, 0); \
      acc[0][1] = __builtin_amdgcn_mfma_f32_16x16x32_bf16(a0, b1, acc[0][1], 0, 0, 0); \
      acc[0][2] = __builtin_amdgcn_mfma_f32_16x16x32_bf16(a0, b2, acc[0][2], 0, 0, 0); \
      acc[0][3] = __builtin_amdgcn_mfma_f32_16x16x32_bf16(a0, b3, acc[0][3], 0, 0, 0); \
      acc[1][0] = __builtin_amdgcn_mfma_f32_16x16x32_bf16(a1, b0, acc[1][0], 0, 0, 0); \
      acc[1][1] = __builtin_amdgcn_mfma_f32_16x16x32_bf16(a1, b1, acc[1][1], 0, 0, 0); \
      acc[1][2] = __builtin_amdgcn_mfma_f32_16x16x32_bf16(a1, b2, acc[1][2], 0, 0, 0); \
      acc[1][3] = __builtin_amdgcn_mfma_f32_16x16x32_bf16(a1, b3, acc[1][3], 0, 0, 0); \
      __builtin_amdgcn_s_setprio(0);                                           \
      /* phase 1: A m2,m3; stage kt+2's B-units */                             \
      short8 a2 = AFRAG(cur, 2), a3 = AFRAG(cur, 3);                           \
      if (more) {                                                              \
        gload16((pb), stg + 8192 + w * 1024);                                  \
        gload16((pb) + (size_t)64 * (KK), stg + 12288 + w * 1024);             \
        (pa) += BK; (pb) += BK;                                                \
      }                                                                        \
      asm volatile("s_waitcnt lgkmcnt(0)" ::: "memory");                       \
      __builtin_amdgcn_sched_barrier(0);                                       \
      __builtin_amdgcn_s_setprio(1);                                           \
      acc[2][0] = __builtin_amdgcn_mfma_f32_16x16x32_bf16(a2, b0, acc[2][0], 0, 0, 0); \
      acc[2][1] = __builtin_amdgcn_mfma_f32_16x16x32_bf16(a2, b1, acc[2][1], 0, 0, 0); \
      acc[2][2] = __builtin_amdgcn_mfma_f32_16x16x32_bf16(a2, b2, acc[2][2], 0, 0, 0); \
      acc[2][3] = __builtin_amdgcn_mfma_f32_16x16x32_bf16(a2, b3, acc[2][3], 0, 0, 0); \
      acc[3][0] = __builtin_amdgcn_mfma_f32_16x16x32_bf16(a3, b0, acc[3][0], 0, 0, 0); \
      acc[3][1] = __builtin_amdgcn_mfma_f32_16x16x32_bf16(a3, b1, acc[3][1], 0, 0, 0); \
      acc[3][2] = __builtin_amdgcn_mfma_f32_16x16x32_bf16(a3, b2, acc[3][2], 0, 0, 0); \
      acc[3][3] = __builtin_amdgcn_mfma_f32_16x16x32_bf16(a3, b3, acc[3][3], 0, 0, 0); \
      __builtin_amdgcn_s_setprio(0);                                           \
      /* K-tile boundary: certify kt+1 (oldest 4 loads), keep kt+2 in flight */\
      if (kt + 1 < NT) {                                                       \
        if (more) { asm volatile("s_waitcnt vmcnt(4)" ::: "memory"); }         \
        else      { asm volatile("s_waitcnt vmcnt(0)" ::: "memory"); }         \
        __builtin_amdgcn_s_barrier();                                          \
      }                                                                        \
      char* tmp = cur; cur = nxt; nxt = stg; stg = tmp;                        \
    }                                                                          \
  }

// ---------------- GEMM: C = relu(A @ Bt^T + bias) -> bf16 ----------------
template <int K>
__global__ __launch_bounds__(256) void k_gemm_relu(
    const bf16* __restrict__ A, const bf16* __restrict__ Bt,
    const float* __restrict__ bias, bf16* __restrict__ Out, int N) {
  __shared__ char ldsbuf[49152];   // 3 x 16 KB K-tile ring
  const int t = threadIdx.x, w = t >> 6, l = t & 63;
  const int wr = w >> 1, wc = w & 1;
  const int bm0 = blockIdx.y * BM, bn0 = blockIdx.x * BN;
  const int lr = l & 15;
  f32x4 acc[4][4] = {};

  const bf16* pA = A + (size_t)(bm0 + (t >> 2)) * K + (t & 3) * 8;
  const bf16* pB = Bt + (size_t)(bn0 + (t >> 2)) * K + (t & 3) * 8;
  KLOOP3(pA, pB, K)

#pragma unroll
  for (int m = 0; m < 4; ++m) {
#pragma unroll
    for (int n = 0; n < 4; ++n) {
      int col = bn0 + wc * 64 + n * 16 + lr;
      float bv = bias[col];
#pragma unroll
      for (int r = 0; r < 4; ++r) {
        int row = bm0 + wr * 64 + m * 16 + (l >> 4) * 4 + r;
        float v = acc[m][n][r] + bv;
        v = v > 0.f ? v : 0.f;
        Out[(size_t)row * N + col] = __float2bfloat16(v);
      }
    }
  }
}

// ---------------- GEMM3: dense per-head GEMM on padded-sorted rows ----------------
// grid (NA/BN=4, PADM/BM=132) = 528 blocks. Head from poff; softplus+1;
// scatter store via rowid.
__global__ __launch_bounds__(256) void k_gemm_head(
    const bf16* __restrict__ H,      // [PADM][HID] padded-sorted
    const bf16* __restrict__ Wht,    // [NE][NA][HID]
    const float* __restrict__ bh,    // [NE][NA]
    const int* __restrict__ poff,    // [NE+1]
    const int* __restrict__ cnt,     // [NE]
    const int* __restrict__ rowid,   // [PADM]
    float* __restrict__ Out) {
  const int mb0 = blockIdx.y * BM;
  if (mb0 >= poff[NE]) return;   // block-uniform exit (before any barrier)
  int e = 0;
#pragma unroll
  for (int k = 1; k < NE; ++k) if (mb0 >= poff[k]) e = k;
  const int pend = poff[e] + cnt[e];   // rows >= pend are padding

  __shared__ char ldsbuf[49152];
  const int t = threadIdx.x, w = t >> 6, l = t & 63;
  const int wr = w >> 1, wc = w & 1;
  const int bn0 = blockIdx.x * BN;
  const int lr = l & 15;
  const bf16* Wt = Wht + (size_t)e * NA * HID;
  f32x4 acc[4][4] = {};

  const bf16* pA = H + (size_t)(mb0 + (t >> 2)) * HID + (t & 3) * 8;
  const bf16* pB = Wt + (size_t)(bn0 + (t >> 2)) * HID + (t & 3) * 8;
  KLOOP3(pA, pB, HID)

#pragma unroll
  for (int m = 0; m < 4; ++m) {
#pragma unroll
    for (int r = 0; r < 4; ++r) {
      int ps = mb0 + wr * 64 + m * 16 + (l >> 4) * 4 + r;
      if (ps < pend) {
        int row = rowid[ps];
#pragma unroll
        for (int n = 0; n < 4; ++n) {
          int col = bn0 + wc * 64 + n * 16 + lr;
          float v = acc[m][n][r] + bh[e * NA + col];
          float sp = (v > 20.f) ? v : log1pf(expf(v));
          Out[(size_t)row * NA + col] = sp + 1.f;
        }
      }
    }
  }
}

// ---------------- launch ----------------
extern "C" void kernel_launch(void* const* d_in, const int* in_sizes, int n_in,
                              void* d_out, int out_size, void* d_ws, size_t ws_size,
                              hipStream_t stream) {
  const float* x  = (const float*)d_in[0];
  const float* W1 = (const float*)d_in[1];
  const float* b1 = (const float*)d_in[2];
  const float* W2 = (const float*)d_in[3];
  const float* b2 = (const float*)d_in[4];
  const float* Wh = (const float*)d_in[5];
  const float* bh = (const float*)d_in[6];
  float* out = (float*)d_out;

  // workspace carve (all 256B-aligned)
  char* p = (char*)d_ws;
  bf16* xb  = (bf16*)p; p += (size_t)PADM * INDIM * 2;  // 8.7 MiB (permuted)
  bf16* w1t = (bf16*)p; p += (size_t)HID * INDIM * 2;   // 512 KiB
  bf16* w2t = (bf16*)p; p += (size_t)HID * HID * 2;     // 2 MiB
  bf16* wht = (bf16*)p; p += (size_t)NE * NA * HID * 2; // 4 MiB
  bf16* h1b = (bf16*)p; p += (size_t)PADM * HID * 2;    // 34.6 MiB (permuted)
  bf16* h2b = (bf16*)p; p += (size_t)PADM * HID * 2;    // 34.6 MiB (permuted)
  int* sortidx = (int*)p; p += (size_t)BSZ * 4;         // orig -> padded pos
  int* rowid   = (int*)p; p += (size_t)PADM * 4;        // padded pos -> orig
  int* cnt    = (int*)p; p += 256;
  int* poff   = (int*)p; p += 256;
  int* cursor = (int*)p; p += 256;

  const int MB = PADM / BM;  // 132 m-blocks over padded row space

  // routing (counting sort of rows by regime, hierarchical histogram)
  k_zero<<<1, 64, 0, stream>>>(cnt, cursor);
  k_count<<<BSZ / 256, 256, 0, stream>>>(x, cnt);
  k_prefix<<<1, 64, 0, stream>>>(cnt, poff);
  k_scatter<<<BSZ / 256, 256, 0, stream>>>(x, poff, cursor, sortidx, rowid);

  // bf16 conversions (x cast lands in permuted row order)
  k_cast_perm<<<BSZ * (INDIM / 8) / 256, 256, 0, stream>>>(x, sortidx, xb);
  k_transpose<<<dim3(HID / 32, INDIM / 32, 1), dim3(32, 8), 0, stream>>>(W1, w1t, INDIM, HID);
  k_transpose<<<dim3(HID / 32, HID / 32, 1), dim3(32, 8), 0, stream>>>(W2, w2t, HID, HID);
  k_transpose<<<dim3(NA / 32, HID / 32, NE), dim3(32, 8), 0, stream>>>(Wh, wht, HID, NA);

  // GEMM1: h1 = relu(xs @ W1 + b1)   (padded rows compute garbage, masked later)
  k_gemm_relu<INDIM><<<dim3(HID / BN, MB), 256, 0, stream>>>(xb, w1t, b1, h1b, HID);
  // GEMM2: h2 = relu(h1 @ W2 + b2)
  k_gemm_relu<HID><<<dim3(HID / BN, MB), 256, 0, stream>>>(h1b, w2t, b2, h2b, HID);
  // GEMM3: dense per-head, softplus+1, scatter store via rowid
  k_gemm_head<<<dim3(NA / BN, MB), 256, 0, stream>>>(h2b, wht, bh, poff, cnt, rowid, out);
}